// Round 1
// 170.062 us; speedup vs baseline: 1.0011x; 1.0011x over previous
//
#include <hip/hip_runtime.h>
#include <hip/hip_bf16.h>

#define KN  2048   // nodes
#define KD  256    // emb dim = HF
#define KH  4      // heads
#define KF  64     // feat/head
#define KT  64     // time steps
#define NCS 32     // colsum partial buffers

typedef __attribute__((ext_vector_type(8))) short short8;
typedef __attribute__((ext_vector_type(4))) short short4v;
typedef __attribute__((ext_vector_type(4))) float floatx4;

// ---------------- helpers ----------------
__device__ __forceinline__ float wave_sum(float v) {
    #pragma unroll
    for (int o = 32; o > 0; o >>= 1) v += __shfl_xor(v, o, 64);
    return v;
}
__device__ __forceinline__ float wave_max(float v) {
    #pragma unroll
    for (int o = 32; o > 0; o >>= 1) v = fmaxf(v, __shfl_xor(v, o, 64));
    return v;
}
__device__ __forceinline__ short f2bs(float x) {
    union { __hip_bfloat16 h; short s; } u;
    u.h = __float2bfloat16(x);
    return u.s;
}

// ---------------- K0: setup = ycs normalize + bf16 conversions ----------
// blocks [0,512):    ycs normalization (4 rows/block)
// blocks [512,768):  emb -> bf16 (row-major, unchanged layout)
// blocks [768,896):  8 weight matrices 256x256 -> transposed bf16 [n][k]
struct CvtPtrs {
    const float* emb; short* emb_bf;
    const float* src[8];
    short* dst[8];
};
__global__ __launch_bounds__(256) void setup_kernel(const float* __restrict__ y,
                                                    float* __restrict__ ycs,
                                                    CvtPtrs cp) {
    __shared__ float tl[64][65];
    int blk = blockIdx.x;
    int t = threadIdx.x;
    if (blk < 512) {
        int w = t >> 6, lane = t & 63;
        int n = blk * 4 + w;
        float v = y[n * KT + lane];
        float mean = wave_sum(v) * (1.0f / KT);
        float yc = v - mean;
        float ss = wave_sum(yc * yc);
        ycs[n * KT + lane] = yc * rsqrtf(ss * (1.0f / (KT - 1)));
        return;
    }
    if (blk < 768) {   // emb convert: 256 blocks x 256 threads x 8 elems
        int base = (blk - 512) * 2048 + t * 8;
        float4 a = *reinterpret_cast<const float4*>(&cp.emb[base]);
        float4 b = *reinterpret_cast<const float4*>(&cp.emb[base + 4]);
        short8 v;
        v[0] = f2bs(a.x); v[1] = f2bs(a.y); v[2] = f2bs(a.z); v[3] = f2bs(a.w);
        v[4] = f2bs(b.x); v[5] = f2bs(b.y); v[6] = f2bs(b.z); v[7] = f2bs(b.w);
        *reinterpret_cast<short8*>(&cp.emb_bf[base]) = v;
        return;
    }
    // weight transpose: 8 matrices x 16 tiles of 64x64
    int b = blk - 768;
    int m = b >> 4, tile = b & 15;
    int ti = tile >> 2, tj = tile & 3;       // ti: k-tile, tj: n-tile
    const float* W = cp.src[m];
    short* WT = cp.dst[m];
    int n = t & 63, kg = (t >> 6) * 16;
    #pragma unroll
    for (int r2 = 0; r2 < 16; r2++)
        tl[n][kg + r2] = W[(size_t)(ti * 64 + kg + r2) * KD + tj * 64 + n];
    __syncthreads();
    int nr = t >> 2, kc = (t & 3) * 16;
    short8 v0, v1;
    #pragma unroll
    for (int c = 0; c < 8; c++) v0[c] = f2bs(tl[nr][kc + c]);
    #pragma unroll
    for (int c = 0; c < 8; c++) v1[c] = f2bs(tl[nr][kc + 8 + c]);
    size_t o = (size_t)(tj * 64 + nr) * KD + ti * 64 + kc;
    *reinterpret_cast<short8*>(&WT[o]) = v0;
    *reinterpret_cast<short8*>(&WT[o + 8]) = v1;
}

// ---------------- corr body: upper-tri 64x64 tile, writes (i,j) AND (j,i) --
__device__ __forceinline__ void corr_body(const float* __restrict__ ycs,
                                          const float* __restrict__ adj,
                                          unsigned char* __restrict__ code,
                                          int blk, char* smem) {
    float (*As)[68] = (float(*)[68])smem;            // 16x68 f32
    float (*Bs)[68] = (float(*)[68])(smem + 4352);
    int bi = 0, rem = blk;
    while (rem >= 32 - bi) { rem -= 32 - bi; bi++; }
    int bj = bi + rem;
    int i0 = bi * 64, j0 = bj * 64;
    int t = threadIdx.x;
    int tx = t & 15, ty = t >> 4;
    int ar = t >> 2, ac = (t & 3) * 4;
    float acc[4][4] = {};
    for (int kt = 0; kt < KT; kt += 16) {
        float4 a4 = *reinterpret_cast<const float4*>(&ycs[(size_t)(i0 + ar) * KT + kt + ac]);
        float4 b4 = *reinterpret_cast<const float4*>(&ycs[(size_t)(j0 + ar) * KT + kt + ac]);
        As[ac + 0][ar] = a4.x; As[ac + 1][ar] = a4.y; As[ac + 2][ar] = a4.z; As[ac + 3][ar] = a4.w;
        Bs[ac + 0][ar] = b4.x; Bs[ac + 1][ar] = b4.y; Bs[ac + 2][ar] = b4.z; Bs[ac + 3][ar] = b4.w;
        __syncthreads();
        #pragma unroll
        for (int kk = 0; kk < 16; kk++) {
            float4 av = *reinterpret_cast<const float4*>(&As[kk][ty * 4]);
            float4 bv = *reinterpret_cast<const float4*>(&Bs[kk][tx * 4]);
            float a4v[4] = {av.x, av.y, av.z, av.w};
            float b4v[4] = {bv.x, bv.y, bv.z, bv.w};
            #pragma unroll
            for (int ii = 0; ii < 4; ii++)
                #pragma unroll
                for (int jj = 0; jj < 4; jj++) acc[ii][jj] += a4v[ii] * b4v[jj];
        }
        __syncthreads();
    }
    #pragma unroll
    for (int ii = 0; ii < 4; ii++) {
        int i = i0 + ty * 4 + ii;
        int jb = j0 + tx * 4;
        float4 av4 = *reinterpret_cast<const float4*>(&adj[(size_t)i * KN + jb]);
        float a4v[4] = {av4.x, av4.y, av4.z, av4.w};
        uchar4 cc;
        unsigned char* c = (unsigned char*)&cc;
        #pragma unroll
        for (int jj = 0; jj < 4; jj++)
            c[jj] = (a4v[jj] != 0.0f) ? ((acc[ii][jj] >= 0.1f) ? 1 : 2) : 0;
        *reinterpret_cast<uchar4*>(&code[(size_t)i * KN + jb]) = cc;
    }
    if (bi != bj) {
        #pragma unroll
        for (int jj = 0; jj < 4; jj++) {
            int j = j0 + tx * 4 + jj;
            int ib = i0 + ty * 4;
            float4 av4 = *reinterpret_cast<const float4*>(&adj[(size_t)j * KN + ib]);
            float a4v[4] = {av4.x, av4.y, av4.z, av4.w};
            uchar4 cc;
            unsigned char* c = (unsigned char*)&cc;
            #pragma unroll
            for (int ii = 0; ii < 4; ii++)
                c[ii] = (a4v[ii] != 0.0f) ? ((acc[ii][jj] >= 0.1f) ? 1 : 2) : 0;
            *reinterpret_cast<uchar4*>(&code[(size_t)j * KN + ib]) = cc;
        }
    }
}

// ---------------- MFMA bf16 GEMM body: 64x64 C tile, K=256, bf16 inputs ----
// A bf16 [M][256] row-major, BT bf16 [Ncols][256] row-major (row n = out col).
// bias pre-offset to the 64-entry tile slice (or null). Cbf optional bf16
// shadow copy. Optional fused f1/f2 head reduction.
template <bool TANH>
__device__ __forceinline__ void mfma_gemm_body(
    const short* __restrict__ A, int bm,
    const short* __restrict__ BT, int bn,
    const float* __restrict__ bias,
    float* __restrict__ C, int cn,
    short* __restrict__ Cbf,
    float* __restrict__ f1h, float* __restrict__ f2h,
    const float* __restrict__ wu_h, const float* __restrict__ wv_h,
    char* smem)
{
    short* As = (short*)smem;            // [64][40] bf16 (row m, col k)
    short* Bs = (short*)(smem + 5120);   // [64][40] bf16 (row n, col k)
    int t = threadIdx.x;
    int w = t >> 6, lane = t & 63;
    int m16 = lane & 15, kq = lane >> 4;
    floatx4 acc0 = {0,0,0,0}, acc1 = {0,0,0,0}, acc2 = {0,0,0,0}, acc3 = {0,0,0,0};
    int r = t >> 2, ko = (t & 3) * 8;
    const short* pa = &A[(size_t)(bm + r) * KD + ko];
    const short* pb = &BT[(size_t)(bn + r) * KD + ko];
    for (int kt = 0; kt < KD; kt += 32) {
        short8 av = *reinterpret_cast<const short8*>(pa + kt);
        short8 bv = *reinterpret_cast<const short8*>(pb + kt);
        __syncthreads();   // previous iteration's frag reads complete
        *reinterpret_cast<short8*>(&As[r * 40 + ko]) = av;
        *reinterpret_cast<short8*>(&Bs[r * 40 + ko]) = bv;
        __syncthreads();
        short8 af  = *reinterpret_cast<short8*>(&As[(w * 16 + m16) * 40 + kq * 8]);
        short8 bf0 = *reinterpret_cast<short8*>(&Bs[( 0 + m16) * 40 + kq * 8]);
        short8 bf1 = *reinterpret_cast<short8*>(&Bs[(16 + m16) * 40 + kq * 8]);
        short8 bf2 = *reinterpret_cast<short8*>(&Bs[(32 + m16) * 40 + kq * 8]);
        short8 bf3 = *reinterpret_cast<short8*>(&Bs[(48 + m16) * 40 + kq * 8]);
        acc0 = __builtin_amdgcn_mfma_f32_16x16x32_bf16(af, bf0, acc0, 0, 0, 0);
        acc1 = __builtin_amdgcn_mfma_f32_16x16x32_bf16(af, bf1, acc1, 0, 0, 0);
        acc2 = __builtin_amdgcn_mfma_f32_16x16x32_bf16(af, bf2, acc2, 0, 0, 0);
        acc3 = __builtin_amdgcn_mfma_f32_16x16x32_bf16(af, bf3, acc3, 0, 0, 0);
    }
    // epilogue: C/D layout col=lane&15, row=(lane>>4)*4+reg
    int row0 = bm + w * 16 + kq * 4;
    floatx4 accs[4] = {acc0, acc1, acc2, acc3};
    #pragma unroll
    for (int nb = 0; nb < 4; nb++) {
        #pragma unroll
        for (int rr = 0; rr < 4; rr++) {
            int col = nb * 16 + m16;
            float v = accs[nb][rr] + (bias ? bias[col] : 0.0f);
            if (TANH) {
                float vc = fminf(fmaxf(v, -9.0f), 9.0f);
                float ex = __expf(2.0f * vc);
                v = (ex - 1.0f) / (ex + 1.0f);
            }
            size_t cidx = (size_t)(row0 + rr) * KD + cn + col;
            C[cidx] = v;
            if (Cbf) Cbf[cidx] = f2bs(v);
        }
    }
    if (f1h) {  // fused f1/f2: dot each row with wu/wv over this head's 64 cols
        float wuv[4], wvv[4];
        #pragma unroll
        for (int nb = 0; nb < 4; nb++) { wuv[nb] = wu_h[nb * 16 + m16]; wvv[nb] = wv_h[nb * 16 + m16]; }
        #pragma unroll
        for (int rr = 0; rr < 4; rr++) {
            float p1 = accs[0][rr] * wuv[0] + accs[1][rr] * wuv[1] + accs[2][rr] * wuv[2] + accs[3][rr] * wuv[3];
            float p2 = accs[0][rr] * wvv[0] + accs[1][rr] * wvv[1] + accs[2][rr] * wvv[2] + accs[3][rr] * wvv[3];
            #pragma unroll
            for (int o = 1; o < 16; o <<= 1) {
                p1 += __shfl_xor(p1, o, 64);
                p2 += __shfl_xor(p2, o, 64);
            }
            if (m16 == 0) { f1h[row0 + rr] = p1; f2h[row0 + rr] = p2; }
        }
    }
}

// ---- K1: phase1 = corr upper-tri (528) + emb GEMM (640) + colsum zero (1) --
struct P1Ptrs {
    const short *emb_bf, *pos_wT, *neg_wT, *pos_pwT, *neg_pwT, *self_wT;
    const float *pos_pb, *neg_pb, *self_b;
    const float *pos_wu, *pos_wv, *neg_wu, *neg_wv;
    float *S_pos, *S_neg, *P_pos, *P_neg, *sup;
    short *sup_bf;
    float *f1p, *f2p, *f1n, *f2n;
};
__global__ __launch_bounds__(256, 4) void phase1_kernel(
    const float* __restrict__ ycs, const float* __restrict__ adj,
    unsigned char* __restrict__ code, float* __restrict__ colsum, P1Ptrs p)
{
    __shared__ alignas(16) char smem[10240];
    int blk = blockIdx.x;
    if (blk < 528) {
        corr_body(ycs, adj, code, blk, smem);
        return;
    }
    if (blk >= 1168) {   // colsum zero
        for (int j = threadIdx.x; j < NCS * KD; j += 256) colsum[j] = 0.0f;
        return;
    }
    int b = blk - 528;             // 0..639
    int tn = b % 20, tm = b / 20;
    int buf = tn >> 2, coloff = (tn & 3) * 64;
    int h = tn & 3;
    const short* B; const float* bias = nullptr; float* C; short* Cbf = nullptr;
    float *f1h = nullptr, *f2h = nullptr;
    const float *wu_h = nullptr, *wv_h = nullptr;
    if (buf == 0) {
        B = p.pos_wT;  C = p.S_pos;
        f1h = p.f1p + h * KN; f2h = p.f2p + h * KN;
        wu_h = p.pos_wu + h * KF; wv_h = p.pos_wv + h * KF;
    } else if (buf == 1) {
        B = p.neg_wT;  C = p.S_neg;
        f1h = p.f1n + h * KN; f2h = p.f2n + h * KN;
        wu_h = p.neg_wu + h * KF; wv_h = p.neg_wv + h * KF;
    } else if (buf == 2) { B = p.pos_pwT; bias = p.pos_pb + coloff; C = p.P_pos; }
    else if (buf == 3)   { B = p.neg_pwT; bias = p.neg_pb + coloff; C = p.P_neg; }
    else                 { B = p.self_wT; bias = p.self_b + coloff; C = p.sup; Cbf = p.sup_bf; }
    mfma_gemm_body<false>(p.emb_bf, tm * 64, B, coloff, bias,
                          C, coloff, Cbf, f1h, f2h, wu_h, wv_h, smem);
}

// ---------------- K4: sparse GAT row, block per i, both rels, wave = head --
#define MAXE 256
__global__ __launch_bounds__(256) void attn_kernel(
    const unsigned char* __restrict__ code,
    const float* __restrict__ f1p, const float* __restrict__ f2p,
    const float* __restrict__ Sp, const float* __restrict__ Pp,
    const float* __restrict__ bp, short* __restrict__ Gp,
    const float* __restrict__ f1n, const float* __restrict__ f2n,
    const float* __restrict__ Sn, const float* __restrict__ Pn,
    const float* __restrict__ bn_, short* __restrict__ Gn)
{
    __shared__ alignas(16) int jl[2][MAXE];
    __shared__ alignas(16) float lg[KH][MAXE];
    __shared__ int cnt[2];
    int i = blockIdx.x;
    int w = threadIdx.x >> 6, lane = threadIdx.x & 63;
    if (threadIdx.x < 2) cnt[threadIdx.x] = 0;
    __syncthreads();
    // cooperative scan: wave w covers columns [w*512, w*512+512), both rels
    #pragma unroll
    for (int it = 0; it < 2; it++) {
        int base = w * 512 + it * 256;
        uchar4 cv = *reinterpret_cast<const uchar4*>(&code[(size_t)i * KN + base + lane * 4]);
        const unsigned char* ce = (const unsigned char*)&cv;
        #pragma unroll
        for (int e = 0; e < 4; e++) {
            #pragma unroll
            for (int rel = 0; rel < 2; rel++) {
                bool pr = (ce[e] == (rel ? (unsigned char)2 : (unsigned char)1));
                unsigned long long bal = __ballot(pr);
                int tot = __popcll(bal);
                int basepos = 0;
                if (lane == 0 && tot) basepos = atomicAdd(&cnt[rel], tot);
                basepos = __shfl(basepos, 0, 64);
                if (pr) {
                    int idx = basepos + __popcll(bal & ((1ull << lane) - 1ull));
                    if (idx < MAXE) jl[rel][idx] = base + lane * 4 + e;
                }
            }
        }
    }
    __syncthreads();
    int c0 = cnt[0]; if (c0 > MAXE) c0 = MAXE;
    int c1 = cnt[1]; if (c1 > MAXE) c1 = MAXE;
    // pad both lists to multiple of 4 with valid index 0 (weight zeroed later)
    if (threadIdx.x < 4) {
        int cR = (c0 + 3) & ~3;
        if (c0 + threadIdx.x < cR) jl[0][c0 + threadIdx.x] = 0;
    } else if (threadIdx.x < 8) {
        int l2 = threadIdx.x - 4;
        int cR = (c1 + 3) & ~3;
        if (c1 + l2 < cR) jl[1][c1 + l2] = 0;
    }
    __syncthreads();
    int h = w;                                  // one wave per head
    int g = lane >> 4, q4 = (lane & 15) * 4;
    for (int rel = 0; rel < 2; rel++) {
        const float* f1 = rel ? f1n : f1p;
        const float* f2 = rel ? f2n : f2p;
        const float* S  = rel ? Sn : Sp;
        const float* P  = rel ? Pn : Pp;
        const float* b  = rel ? bn_ : bp;
        short* G        = rel ? Gn : Gp;
        int count = rel ? c1 : c0;
        int countR = (count + 3) & ~3;
        float f2i = f2[h * KN + i];
        float m = -1e30f;
        for (int k = lane; k < count; k += 64) {
            int j = jl[rel][k];
            float x = f1[h * KN + j] + f2i;
            x = (x > 0.0f) ? x : 0.2f * x;      // leaky_relu 0.2
            lg[h][k] = x;
            m = fmaxf(m, x);
        }
        m = wave_max(m);
        float ps = 0.0f;
        for (int k = lane; k < count; k += 64) {
            float e = __expf(lg[h][k] - m);
            lg[h][k] = e;
            ps += e;
        }
        float denom = wave_sum(ps);
        for (int k2 = count + lane; k2 < countR; k2 += 64) lg[h][k2] = 0.0f;
        // gather: 16 lanes x float4 per j, 4 j's per iteration
        const float* Sh4 = S + h * KF + q4;
        float ax = 0.0f, ay = 0.0f, az = 0.0f, aw = 0.0f;
        for (int k = 0; k < countR; k += 4) {
            int j = jl[rel][k + g];
            float wgt = lg[h][k + g];
            float4 sv = *reinterpret_cast<const float4*>(&Sh4[(size_t)j * KD]);
            ax += wgt * sv.x; ay += wgt * sv.y; az += wgt * sv.z; aw += wgt * sv.w;
        }
        #pragma unroll
        for (int o = 16; o < 64; o <<= 1) {
            ax += __shfl_xor(ax, o, 64); ay += __shfl_xor(ay, o, 64);
            az += __shfl_xor(az, o, 64); aw += __shfl_xor(aw, o, 64);
        }
        if (g == 0) {
            float inv = count ? (1.0f / denom) : 0.0f;
            int col = h * KF + q4;
            size_t idx = (size_t)i * KD + col;
            float4 pv = *reinterpret_cast<const float4*>(&P[idx]);
            short4v o4;
            o4[0] = f2bs(ax * inv + b[col + 0] + pv.x);
            o4[1] = f2bs(ay * inv + b[col + 1] + pv.y);
            o4[2] = f2bs(az * inv + b[col + 2] + pv.z);
            o4[3] = f2bs(aw * inv + b[col + 3] + pv.w);
            *reinterpret_cast<short4v*>(&G[idx]) = o4;
        }
    }
}

// K2: [G_pos;G_neg]bf16 (4096x256) @ {mlp_pos|mlp_neg}T -> [psup;nsup] (+bf16),
//     plus T0 = tanh(sup @ sem_w1 + sem_b1) on blocks by>=64
__global__ __launch_bounds__(256, 4) void gemm_mlp(const short* __restrict__ Astack,
                                                   const short* __restrict__ B0T,
                                                   const short* __restrict__ B1T,
                                                   const float* __restrict__ b0,
                                                   const float* __restrict__ b1,
                                                   float* __restrict__ Cstack,
                                                   short* __restrict__ Cstack_bf,
                                                   const short* __restrict__ sup_bf,
                                                   const short* __restrict__ semw1T,
                                                   const float* __restrict__ semb1,
                                                   float* __restrict__ T0) {
    __shared__ alignas(16) char smem[10240];
    int by = blockIdx.y;
    int cn = blockIdx.x * 64;
    if (by < 64) {
        int bm = by * 64;
        bool sel = bm >= KN;
        mfma_gemm_body<false>(Astack, bm, sel ? B1T : B0T, cn,
                              (sel ? b1 : b0) + cn, Cstack, cn, Cstack_bf,
                              nullptr, nullptr, nullptr, nullptr, smem);
    } else {
        int bm = (by - 64) * 64;
        mfma_gemm_body<true>(sup_bf, bm, semw1T, cn,
                             semb1 + cn, T0, cn, nullptr,
                             nullptr, nullptr, nullptr, nullptr, smem);
    }
}

// K3: [psup;nsup]bf16 (4096x256) @ sem_w1T + b, tanh -> [T1;T2]
__global__ __launch_bounds__(256, 4) void gemm_sem(const short* __restrict__ Astack,
                                                   const short* __restrict__ BT,
                                                   const float* __restrict__ bias,
                                                   float* __restrict__ Cstack) {
    __shared__ alignas(16) char smem[10240];
    int cn = blockIdx.x * 64;
    mfma_gemm_body<true>(Astack, blockIdx.y * 64, BT, cn,
                         bias + cn, Cstack, cn, nullptr,
                         nullptr, nullptr, nullptr, nullptr, smem);
}

// ---------------- K5: semantic attention blend + colsum partials --------
__global__ __launch_bounds__(256) void combine_kernel(const float* __restrict__ T0,
                                                      const float* __restrict__ T1,
                                                      const float* __restrict__ T2,
                                                      const float* __restrict__ w2,
                                                      const float* __restrict__ sup,
                                                      const float* __restrict__ psup,
                                                      const float* __restrict__ nsup,
                                                      float* __restrict__ X,
                                                      float* __restrict__ colsum) {
    int n = blockIdx.x, d = threadIdx.x;
    size_t idx = (size_t)n * KD + d;
    float w2d = w2[d];
    float p0 = T0[idx] * w2d, p1 = T1[idx] * w2d, p2 = T2[idx] * w2d;
    __shared__ float sbuf[4][3];
    int wv = d >> 6, lane = d & 63;
    float s0 = wave_sum(p0), s1 = wave_sum(p1), s2 = wave_sum(p2);
    if (lane == 0) { sbuf[wv][0] = s0; sbuf[wv][1] = s1; sbuf[wv][2] = s2; }
    __syncthreads();
    float w0 = sbuf[0][0] + sbuf[1][0] + sbuf[2][0] + sbuf[3][0];
    float w1 = sbuf[0][1] + sbuf[1][1] + sbuf[2][1] + sbuf[3][1];
    float w2l = sbuf[0][2] + sbuf[1][2] + sbuf[2][2] + sbuf[3][2];
    float mm = fmaxf(w0, fmaxf(w1, w2l));
    float e0 = __expf(w0 - mm), e1 = __expf(w1 - mm), e2 = __expf(w2l - mm);
    float inv = 1.0f / (e0 + e1 + e2);
    float x = (e0 * inv) * sup[idx] + (e1 * inv) * psup[idx] + (e2 * inv) * nsup[idx];
    X[idx] = x;
    atomicAdd(&colsum[(n & (NCS - 1)) * KD + d], x);
}

// ---------------- K6: PairNorm PN-SI + store ----------------
__global__ __launch_bounds__(256) void final_kernel(const float* __restrict__ X,
                                                    const float* __restrict__ colsum,
                                                    float* __restrict__ out) {
    int n = blockIdx.x, d = threadIdx.x;
    float cs = 0.0f;
    #pragma unroll
    for (int r = 0; r < NCS; r++) cs += colsum[r * KD + d];
    float mean = cs * (1.0f / KN);
    float xc = X[(size_t)n * KD + d] - mean;
    __shared__ float sbuf[4];
    int wv = d >> 6, lane = d & 63;
    float s = wave_sum(xc * xc);
    if (lane == 0) sbuf[wv] = s;
    __syncthreads();
    float ss = sbuf[0] + sbuf[1] + sbuf[2] + sbuf[3];
    out[(size_t)n * KD + d] = xc * rsqrtf(1e-6f + ss);
}

// ---------------- host ----------------
extern "C" void kernel_launch(void* const* d_in, const int* in_sizes, int n_in,
                              void* d_out, int out_size, void* d_ws, size_t ws_size,
                              hipStream_t stream) {
    typedef const float* fp;
    fp emb    = (fp)d_in[0];
    fp y_as_x = (fp)d_in[1];
    fp adj    = (fp)d_in[2];
    fp pos_w  = (fp)d_in[3],  pos_wu = (fp)d_in[4],  pos_wv = (fp)d_in[5];
    fp pos_b  = (fp)d_in[6],  pos_pw = (fp)d_in[7],  pos_pb = (fp)d_in[8];
    fp neg_w  = (fp)d_in[9],  neg_wu = (fp)d_in[10], neg_wv = (fp)d_in[11];
    fp neg_b  = (fp)d_in[12], neg_pw = (fp)d_in[13], neg_pb = (fp)d_in[14];
    fp self_w = (fp)d_in[15], self_b = (fp)d_in[16];
    fp mlp_pos_w = (fp)d_in[17], mlp_pos_b = (fp)d_in[18];
    fp mlp_neg_w = (fp)d_in[19], mlp_neg_b = (fp)d_in[20];
    fp sem_w1 = (fp)d_in[21], sem_b1 = (fp)d_in[22], sem_w2 = (fp)d_in[23];
    float* out = (float*)d_out;

    char* ws = (char*)d_ws;
    size_t off = 0;
    auto alloc = [&](size_t sz) -> char* {
        char* p = ws + off;
        off += (sz + 511) & ~(size_t)511;
        return p;
    };
    const size_t MAT_F32 = (size_t)KN * KD * 4;   // 2 MB
    const size_t MAT_BF  = (size_t)KN * KD * 2;   // 1 MB
    const size_t W_BF    = (size_t)KD * KD * 2;   // 128 KB

    float* ycs         = (float*)alloc((size_t)KN * KT * 4);
    unsigned char* cd  = (unsigned char*)alloc((size_t)KN * KN);
    float* S_pos       = (float*)alloc(MAT_F32);
    float* S_neg       = (float*)alloc(MAT_F32);
    float* P_pos       = (float*)alloc(MAT_F32);
    float* P_neg       = (float*)alloc(MAT_F32);
    float* sup         = (float*)alloc(MAT_F32);
    float* psup        = (float*)alloc(2 * MAT_F32);   // psup|nsup contiguous
    float* nsup        = psup + (size_t)KN * KD;
    float* T0          = (float*)alloc(MAT_F32);
    float* T1          = (float*)alloc(2 * MAT_F32);   // T1|T2 contiguous
    float* T2          = T1 + (size_t)KN * KD;
    float* X           = (float*)alloc(MAT_F32);
    float* colsum      = (float*)alloc((size_t)NCS * KD * 4);
    float* f1p         = (float*)alloc((size_t)KH * KN * 4);
    float* f2p         = (float*)alloc((size_t)KH * KN * 4);
    float* f1n         = (float*)alloc((size_t)KH * KN * 4);
    float* f2n         = (float*)alloc((size_t)KH * KN * 4);
    short* emb_bf      = (short*)alloc(MAT_BF);
    short* G_bf        = (short*)alloc(2 * MAT_BF);    // G_pos|G_neg contiguous
    short* Gp_bf       = G_bf;
    short* Gn_bf       = G_bf + (size_t)KN * KD;
    short* sup_bf      = (short*)alloc(MAT_BF);
    short* ps_bf       = (short*)alloc(2 * MAT_BF);    // psup|nsup bf16 contiguous
    short* pos_wT      = (short*)alloc(W_BF);
    short* neg_wT      = (short*)alloc(W_BF);
    short* pos_pwT     = (short*)alloc(W_BF);
    short* neg_pwT     = (short*)alloc(W_BF);
    short* self_wT     = (short*)alloc(W_BF);
    short* mlp_posT    = (short*)alloc(W_BF);
    short* mlp_negT    = (short*)alloc(W_BF);
    short* semw1T      = (short*)alloc(W_BF);

    CvtPtrs cp;
    cp.emb = emb; cp.emb_bf = emb_bf;
    cp.src[0] = pos_w;     cp.dst[0] = pos_wT;
    cp.src[1] = neg_w;     cp.dst[1] = neg_wT;
    cp.src[2] = pos_pw;    cp.dst[2] = pos_pwT;
    cp.src[3] = neg_pw;    cp.dst[3] = neg_pwT;
    cp.src[4] = self_w;    cp.dst[4] = self_wT;
    cp.src[5] = mlp_pos_w; cp.dst[5] = mlp_posT;
    cp.src[6] = mlp_neg_w; cp.dst[6] = mlp_negT;
    cp.src[7] = sem_w1;    cp.dst[7] = semw1T;

    setup_kernel<<<512 + 256 + 128, 256, 0, stream>>>(y_as_x, ycs, cp);

    P1Ptrs p1;
    p1.emb_bf = emb_bf;
    p1.pos_wT = pos_wT; p1.neg_wT = neg_wT;
    p1.pos_pwT = pos_pwT; p1.neg_pwT = neg_pwT; p1.self_wT = self_wT;
    p1.pos_pb = pos_pb; p1.neg_pb = neg_pb; p1.self_b = self_b;
    p1.pos_wu = pos_wu; p1.pos_wv = pos_wv; p1.neg_wu = neg_wu; p1.neg_wv = neg_wv;
    p1.S_pos = S_pos; p1.S_neg = S_neg; p1.P_pos = P_pos; p1.P_neg = P_neg;
    p1.sup = sup; p1.sup_bf = sup_bf;
    p1.f1p = f1p; p1.f2p = f2p; p1.f1n = f1n; p1.f2n = f2n;

    phase1_kernel<<<528 + 640 + 1, 256, 0, stream>>>(ycs, adj, cd, colsum, p1);

    attn_kernel<<<KN, 256, 0, stream>>>(cd,
                                        f1p, f2p, S_pos, P_pos, pos_b, Gp_bf,
                                        f1n, f2n, S_neg, P_neg, neg_b, Gn_bf);

    gemm_mlp<<<dim3(4, 96), 256, 0, stream>>>(G_bf, mlp_posT, mlp_negT,
                                              mlp_pos_b, mlp_neg_b, psup, ps_bf,
                                              sup_bf, semw1T, sem_b1, T0);
    gemm_sem<<<dim3(4, 64), 256, 0, stream>>>(ps_bf, semw1T, sem_b1, T1);

    combine_kernel<<<KN, 256, 0, stream>>>(T0, T1, T2, sem_w2, sup, psup, nsup, X, colsum);
    final_kernel<<<KN, 256, 0, stream>>>(X, colsum, out);
}